// Round 3
// baseline (1119.544 us; speedup 1.0000x reference)
//
#include <hip/hip_runtime.h>
#include <stdint.h>

typedef __attribute__((ext_vector_type(8))) __bf16 bf16x8;
typedef __attribute__((ext_vector_type(4))) float f32x4;
typedef __attribute__((ext_vector_type(4))) unsigned int u32x4;

constexpr int B = 8, S = 1024, D = 512, H = 8, DFF = 2048, L = 4, DK = 64;
constexpr int MR = B * S;  // 8192 rows

__device__ __forceinline__ unsigned short f2bf(float f) {
    union { float f; unsigned u; } v; v.f = f;
    unsigned u = v.u;
    u += 0x7fffu + ((u >> 16) & 1u);   // RNE
    return (unsigned short)(u >> 16);
}

__device__ __forceinline__ void gload_lds16(const void* g, void* l) {
    __builtin_amdgcn_global_load_lds(
        (const __attribute__((address_space(1))) void*)g,
        (__attribute__((address_space(3))) void*)l, 16, 0, 0);
}

// ---------------- x = qe + pe ; y = qa + pe (f32 + bf16 copies) ----------------
__global__ __launch_bounds__(256) void add_pe_kernel(
    const float* __restrict__ qe, const float* __restrict__ qa,
    const float* __restrict__ pe, float* __restrict__ x_f32,
    unsigned short* __restrict__ x_bf, unsigned short* __restrict__ y_bf) {
    int gid = blockIdx.x * 256 + threadIdx.x;
    int base = gid * 4;
    int po = base & (S * D - 1);
    float4 p = *(const float4*)(pe + po);
    float4 a = *(const float4*)(qe + base);
    float4 q = *(const float4*)(qa + base);
    float4 xv = make_float4(a.x + p.x, a.y + p.y, a.z + p.z, a.w + p.w);
    float4 yv = make_float4(q.x + p.x, q.y + p.y, q.z + p.z, q.w + p.w);
    *(float4*)(x_f32 + base) = xv;
    ushort4 xb; xb.x = f2bf(xv.x); xb.y = f2bf(xv.y); xb.z = f2bf(xv.z); xb.w = f2bf(xv.w);
    ushort4 yb; yb.x = f2bf(yv.x); yb.y = f2bf(yv.y); yb.z = f2bf(yv.z); yb.w = f2bf(yv.w);
    *(ushort4*)(x_bf + base) = xb;
    *(ushort4*)(y_bf + base) = yb;
}

// ---------------- weight prep: f32 [K,N] -> bf16 [N,K], per layer (blockIdx.z) ----------------
__global__ __launch_bounds__(256) void wtrans_kernel(
    const float* __restrict__ src, unsigned short* __restrict__ dst, int K, int N) {
    __shared__ float t[64][65];
    src += (size_t)blockIdx.z * K * N;
    dst += (size_t)blockIdx.z * K * N;
    int n0 = blockIdx.x * 64, k0 = blockIdx.y * 64;
    int tid = threadIdx.x;
    int r = tid >> 4, c4 = (tid & 15) * 4;
    #pragma unroll
    for (int rr = 0; rr < 64; rr += 16) {
        float4 v = *(const float4*)(src + (size_t)(k0 + r + rr) * N + n0 + c4);
        t[r + rr][c4] = v.x; t[r + rr][c4 + 1] = v.y;
        t[r + rr][c4 + 2] = v.z; t[r + rr][c4 + 3] = v.w;
    }
    __syncthreads();
    int n = tid >> 2, kc = (tid & 3) * 16;
    ushort4 o[4];
    #pragma unroll
    for (int g = 0; g < 4; g++) {
        o[g].x = f2bf(t[kc + g * 4 + 0][n]);
        o[g].y = f2bf(t[kc + g * 4 + 1][n]);
        o[g].z = f2bf(t[kc + g * 4 + 2][n]);
        o[g].w = f2bf(t[kc + g * 4 + 3][n]);
    }
    unsigned short* dp = dst + (size_t)(n0 + n) * K + k0 + kc;
    #pragma unroll
    for (int g = 0; g < 4; g++) *(ushort4*)(dp + g * 4) = o[g];
}

// ---------------- GEMM: out = act(A[M,K](bf16) @ Bt[N,K](bf16)^T + bias [+resid]) ----------------
// 128xBN tile, BK=32, global_load_lds width-16 staging, XOR-swizzled unpadded LDS.
template<int BN, bool RELU, bool RESID, bool OUT_F32, bool OUT_BF16, bool OUT_VT>
__global__ __launch_bounds__(256) void gemm_kernel(
    const unsigned short* __restrict__ A, const unsigned short* __restrict__ Bt,
    const float* __restrict__ bias, const float* __restrict__ resid,
    float* __restrict__ out_f32, unsigned short* __restrict__ out_bf,
    int M, int N, int K) {
    constexpr int MT = (BN == 128) ? 4 : 2;
    constexpr int WROWS = (BN == 128) ? 64 : 32;
    __shared__ unsigned short a_lds[128 * 32];
    __shared__ unsigned short b_lds[BN * 32];

    const int tid = threadIdx.x;
    const int lane = tid & 63, wid = tid >> 6;
    const int wm = (BN == 128) ? (wid >> 1) : wid;
    const int wn = (BN == 128) ? (wid & 1) : 0;
    const int l15 = lane & 15, quad = lane >> 4;
    const int m0 = blockIdx.x * 128, n0 = blockIdx.y * BN;

    f32x4 acc[MT][4];
    #pragma unroll
    for (int i = 0; i < MT; i++)
        #pragma unroll
        for (int j = 0; j < 4; j++) { f32x4 z = {0.f, 0.f, 0.f, 0.f}; acc[i][j] = z; }

    // A staging: 512 chunks; wave w covers [w*128, w*128+128)
    const int c0 = wid * 128 + lane, c1 = c0 + 64;
    const int r0 = c0 >> 2, kga0 = (c0 & 3) ^ (r0 & 3);
    const int r1 = c1 >> 2, kga1 = (c1 & 3) ^ (r1 & 3);
    const unsigned short* aP0 = A + (size_t)(m0 + r0) * K + kga0 * 8;
    const unsigned short* aP1 = A + (size_t)(m0 + r1) * K + kga1 * 8;
    unsigned short* aL0 = a_lds + wid * 1024;
    unsigned short* aL1 = aL0 + 512;

    // B staging
    const unsigned short *bP0, *bP1;
    unsigned short *bL0, *bL1;
    if (BN == 128) {
        bP0 = Bt + (size_t)(n0 + r0) * K + kga0 * 8;
        bP1 = Bt + (size_t)(n0 + r1) * K + kga1 * 8;
        bL0 = b_lds + wid * 1024;
        bL1 = bL0 + 512;
    } else {
        int cb = tid, rb = cb >> 2, kgb = (cb & 3) ^ (rb & 3);
        bP0 = Bt + (size_t)(n0 + rb) * K + kgb * 8;
        bP1 = nullptr;
        bL0 = b_lds + wid * 512;
        bL1 = nullptr;
    }

    for (int k0 = 0; k0 < K; k0 += 32) {
        gload_lds16(aP0 + k0, aL0);
        gload_lds16(aP1 + k0, aL1);
        gload_lds16(bP0 + k0, bL0);
        if (BN == 128) gload_lds16(bP1 + k0, bL1);
        __syncthreads();

        bf16x8 af[MT], bfv[4];
        #pragma unroll
        for (int mt = 0; mt < MT; mt++) {
            int row = wm * WROWS + mt * 16 + l15;
            af[mt] = *(const bf16x8*)&a_lds[row * 32 + ((quad ^ (row & 3)) * 8)];
        }
        #pragma unroll
        for (int nt = 0; nt < 4; nt++) {
            int row = wn * 64 + nt * 16 + l15;
            bfv[nt] = *(const bf16x8*)&b_lds[row * 32 + ((quad ^ (row & 3)) * 8)];
        }
        #pragma unroll
        for (int mt = 0; mt < MT; mt++)
            #pragma unroll
            for (int nt = 0; nt < 4; nt++)
                acc[mt][nt] = __builtin_amdgcn_mfma_f32_16x16x32_bf16(af[mt], bfv[nt], acc[mt][nt], 0, 0, 0);
        __syncthreads();
    }

    #pragma unroll
    for (int nt = 0; nt < 4; nt++) {
        int col = n0 + wn * 64 + nt * 16 + l15;
        float bv = bias[col];
        #pragma unroll
        for (int mt = 0; mt < MT; mt++) {
            int row0 = m0 + wm * WROWS + mt * 16 + quad * 4;
            if (OUT_VT) {
                // write V^T layout [B,H,DK,S]; rows s contiguous -> ushort4
                int hh = col >> 6, d = col & 63;
                int bb = row0 >> 10, s0 = row0 & 1023;
                ushort4 o;
                o.x = f2bf(acc[mt][nt][0] + bv);
                o.y = f2bf(acc[mt][nt][1] + bv);
                o.z = f2bf(acc[mt][nt][2] + bv);
                o.w = f2bf(acc[mt][nt][3] + bv);
                *(ushort4*)(out_bf + ((size_t)(bb * H + hh) * DK + d) * S + s0) = o;
            } else {
                #pragma unroll
                for (int r = 0; r < 4; r++) {
                    int row = row0 + r;
                    float v = acc[mt][nt][r] + bv;
                    if (RESID) v += resid[(size_t)row * N + col];
                    if (RELU) v = fmaxf(v, 0.f);
                    size_t o = (size_t)row * N + col;
                    if (OUT_F32) out_f32[o] = v;
                    if (OUT_BF16) out_bf[o] = f2bf(v);
                }
            }
        }
    }
}

// ---------------- LayerNorm over D=512, one block per row ----------------
__global__ __launch_bounds__(256) void ln_kernel(
    const float* __restrict__ in, const float* __restrict__ gamma,
    const float* __restrict__ beta, float* __restrict__ out_f32,
    unsigned short* __restrict__ out_bf) {
    __shared__ float red[8];
    int row = blockIdx.x, tid = threadIdx.x;
    const float* p = in + (size_t)row * D;
    float2 v = *(const float2*)(p + tid * 2);
    float s = v.x + v.y;
    float q = v.x * v.x + v.y * v.y;
    #pragma unroll
    for (int off = 32; off > 0; off >>= 1) {
        s += __shfl_xor(s, off);
        q += __shfl_xor(q, off);
    }
    int wid = tid >> 6, lane = tid & 63;
    if (lane == 0) { red[wid] = s; red[4 + wid] = q; }
    __syncthreads();
    s = red[0] + red[1] + red[2] + red[3];
    q = red[4] + red[5] + red[6] + red[7];
    float mean = s * (1.f / D);
    float var = q * (1.f / D) - mean * mean;
    float inv = rsqrtf(var + 1e-5f);
    int c = tid * 2;
    float2 g = *(const float2*)(gamma + c);
    float2 bb = *(const float2*)(beta + c);
    float o0 = (v.x - mean) * inv * g.x + bb.x;
    float o1 = (v.y - mean) * inv * g.y + bb.y;
    *(float2*)(out_f32 + (size_t)row * D + c) = make_float2(o0, o1);
    ushort2 ob; ob.x = f2bf(o0); ob.y = f2bf(o1);
    *(ushort2*)(out_bf + (size_t)row * D + c) = ob;
}

// ---------------- Flash attention, zero-barrier register-resident ----------------
// Sc^T = K.Q^T  ->  q-row lives on C-layout col (lane&15): softmax lane-uniform.
// One block per (b, h, 64-row q-tile); wave wid owns q-rows wid*16..+15.
__global__ __launch_bounds__(256, 2) void attn_kernel(
    const unsigned short* __restrict__ qk, const unsigned short* __restrict__ vt,
    unsigned short* __restrict__ ob) {
    __shared__ unsigned short o_t[64][72];

    int bx = blockIdx.x;
    int qt = 15 - (bx & 15);        // big blocks first
    int h = (bx >> 4) & 7, b = bx >> 7;
    int tid = threadIdx.x, lane = tid & 63, wid = tid >> 6;
    int l15 = lane & 15, quad = lane >> 4;
    const int rowbase = b * S, colbase = h * DK;

    // Q B-frags (fixed across kt): lane holds Q[q=l15][d=kh*32+quad*8+j]
    const unsigned short* qrow = qk + (size_t)(rowbase + qt * 64 + wid * 16 + l15) * D + colbase;
    bf16x8 qf0 = *(const bf16x8*)(qrow + quad * 8);
    bf16x8 qf1 = *(const bf16x8*)(qrow + 32 + quad * 8);

    const unsigned short* kbase = qk + (size_t)rowbase * D + colbase;
    const unsigned short* vbase = vt + (size_t)(b * H + h) * (DK * S);

    const int gi = qt * 64 + wid * 16 + l15;   // this lane's global q row
    float m_r = -1e30f, l_r = 0.f;
    f32x4 o_acc[4];
    #pragma unroll
    for (int i = 0; i < 4; i++) { f32x4 z = {0.f, 0.f, 0.f, 0.f}; o_acc[i] = z; }

    for (int kt = 0; kt <= qt; kt++) {
        const int mtmax = (kt == qt) ? (wid + 1) : 4;

        // scores Sc^T[s][q]: A = K rows, B = Q rows
        f32x4 s_acc[4];
        #pragma unroll
        for (int mt = 0; mt < 4; mt++) {
            if (mt < mtmax) {
                const unsigned short* kr = kbase + (size_t)(kt * 64 + mt * 16 + l15) * D;
                bf16x8 ka0 = *(const bf16x8*)(kr + quad * 8);
                bf16x8 ka1 = *(const bf16x8*)(kr + 32 + quad * 8);
                f32x4 a = {0.f, 0.f, 0.f, 0.f};
                a = __builtin_amdgcn_mfma_f32_16x16x32_bf16(ka0, qf0, a, 0, 0, 0);
                a = __builtin_amdgcn_mfma_f32_16x16x32_bf16(ka1, qf1, a, 0, 0, 0);
                s_acc[mt] = a;
            }
        }

        // mask + scale + row max (row = q = l15, values spread over mt,r in-lane and quads cross-lane)
        float p[4][4] = {{0.f,0.f,0.f,0.f},{0.f,0.f,0.f,0.f},{0.f,0.f,0.f,0.f},{0.f,0.f,0.f,0.f}};
        float mx = -1e30f;
        #pragma unroll
        for (int mt = 0; mt < 4; mt++) {
            if (mt < mtmax) {
                #pragma unroll
                for (int r = 0; r < 4; r++) {
                    int gj = kt * 64 + mt * 16 + quad * 4 + r;
                    float val = s_acc[mt][r] * 0.125f;
                    if (gj >= gi) val = -1e30f;     // strict causal
                    p[mt][r] = val;
                    mx = fmaxf(mx, val);
                }
            }
        }
        mx = fmaxf(mx, __shfl_xor(mx, 16));
        mx = fmaxf(mx, __shfl_xor(mx, 32));
        float m_new = fmaxf(m_r, mx);
        float alpha = __expf(m_r - m_new);
        float ls = 0.f;
        #pragma unroll
        for (int mt = 0; mt < 4; mt++) {
            if (mt < mtmax) {
                #pragma unroll
                for (int r = 0; r < 4; r++) {
                    float pv = __expf(p[mt][r] - m_new);
                    p[mt][r] = pv;
                    ls += pv;
                }
            }
        }
        ls += __shfl_xor(ls, 16);
        ls += __shfl_xor(ls, 32);
        l_r = l_r * alpha + ls;
        m_r = m_new;

        // pack P to bf16 dwords: pk[mt][0]=(r0,r1), pk[mt][1]=(r2,r3)
        unsigned int pk[4][2];
        #pragma unroll
        for (int mt = 0; mt < 4; mt++) {
            pk[mt][0] = (unsigned)f2bf(p[mt][0]) | ((unsigned)f2bf(p[mt][1]) << 16);
            pk[mt][1] = (unsigned)f2bf(p[mt][2]) | ((unsigned)f2bf(p[mt][3]) << 16);
        }

        // transform to PV B-frags: lane(l15=q) needs P'[s=kh*32+quad*8+j][q]
        bf16x8 pb[2];
        #pragma unroll
        for (int kh = 0; kh < 2; kh++) {
            u32x4 dws;
            #pragma unroll
            for (int dw = 0; dw < 4; dw++) {
                int qs = (2 * quad + (dw >> 1)) & 3;
                int src = qs * 16 + l15;
                int lo = __shfl((int)pk[2 * kh][dw & 1], src, 64);
                int hi = __shfl((int)pk[2 * kh + 1][dw & 1], src, 64);
                unsigned v = (quad >= 2) ? (unsigned)hi : (unsigned)lo;
                if (dw == 0) dws.x = v;
                else if (dw == 1) dws.y = v;
                else if (dw == 2) dws.z = v;
                else dws.w = v;
            }
            pb[kh] = __builtin_bit_cast(bf16x8, dws);
        }

        // rescale O accumulator (alpha is lane-uniform: whole lane is q=l15)
        #pragma unroll
        for (int mt = 0; mt < 4; mt++)
            #pragma unroll
            for (int r = 0; r < 4; r++)
                o_acc[mt][r] *= alpha;

        // O^T += V^T . P' : A = V^T rows (d), B = P'
        #pragma unroll
        for (int mt = 0; mt < 4; mt++) {
            const unsigned short* vr = vbase + (size_t)(mt * 16 + l15) * S + kt * 64;
            bf16x8 va0 = *(const bf16x8*)(vr + quad * 8);
            bf16x8 va1 = *(const bf16x8*)(vr + 32 + quad * 8);
            o_acc[mt] = __builtin_amdgcn_mfma_f32_16x16x32_bf16(va0, pb[0], o_acc[mt], 0, 0, 0);
            o_acc[mt] = __builtin_amdgcn_mfma_f32_16x16x32_bf16(va1, pb[1], o_acc[mt], 0, 0, 0);
        }
    }

    // epilogue: O^T (d on C rows, q on C cols) -> LDS transpose -> coalesced store
    float inv_l = 1.f / l_r;
    #pragma unroll
    for (int mt = 0; mt < 4; mt++)
        #pragma unroll
        for (int r = 0; r < 4; r++)
            o_t[wid * 16 + l15][mt * 16 + quad * 4 + r] = f2bf(o_acc[mt][r] * inv_l);
    __syncthreads();
    int j = tid >> 2, c = (tid & 3) * 16;
    int si = qt * 64 + j;
    unsigned short* dst = ob + (size_t)(rowbase + si) * D + colbase + c;
    if (si == 0) {
        u32x4 z = {0u, 0u, 0u, 0u};
        *(u32x4*)dst = z;
        *(u32x4*)(dst + 8) = z;
    } else {
        *(bf16x8*)dst = *(const bf16x8*)&o_t[j][c];
        *(bf16x8*)(dst + 8) = *(const bf16x8*)&o_t[j][c + 8];
    }
}

// ---------------- driver ----------------
extern "C" void kernel_launch(void* const* d_in, const int* in_sizes, int n_in,
                              void* d_out, int out_size, void* d_ws, size_t ws_size,
                              hipStream_t stream) {
    (void)in_sizes; (void)n_in; (void)out_size; (void)ws_size;
    const float* qe  = (const float*)d_in[0];
    const float* qa  = (const float*)d_in[1];
    const float* pe  = (const float*)d_in[2];
    const float* Wk  = (const float*)d_in[3];
    const float* bk  = (const float*)d_in[4];
    const float* Wv  = (const float*)d_in[5];
    const float* bv  = (const float*)d_in[6];
    const float* Wo  = (const float*)d_in[7];
    const float* bo  = (const float*)d_in[8];
    const float* l1s = (const float*)d_in[9];
    const float* l1b = (const float*)d_in[10];
    const float* W1  = (const float*)d_in[11];
    const float* b1  = (const float*)d_in[12];
    const float* W2  = (const float*)d_in[13];
    const float* b2  = (const float*)d_in[14];
    const float* l2s = (const float*)d_in[15];
    const float* l2b = (const float*)d_in[16];

    char* w = (char*)d_ws;
    float* x_f32  = (float*)w;           w += (size_t)MR * D * 4;
    float* t_f32  = (float*)w;           w += (size_t)MR * D * 4;
    float* x1_f32 = (float*)w;           w += (size_t)MR * D * 4;
    unsigned short* x_bf  = (unsigned short*)w; w += (size_t)MR * D * 2;
    unsigned short* y_bf  = (unsigned short*)w; w += (size_t)MR * D * 2;
    unsigned short* qk_bf = (unsigned short*)w; w += (size_t)MR * D * 2;
    unsigned short* vt_bf = (unsigned short*)w; w += (size_t)MR * D * 2;  // V^T [B,H,DK,S]
    unsigned short* o_bf  = (unsigned short*)w; w += (size_t)MR * D * 2;
    unsigned short* x1_bf = (unsigned short*)w; w += (size_t)MR * D * 2;
    unsigned short* h_bf  = (unsigned short*)w; w += (size_t)MR * DFF * 2;
    unsigned short* wkT = (unsigned short*)w;   w += (size_t)L * D * D * 2;
    unsigned short* wvT = (unsigned short*)w;   w += (size_t)L * D * D * 2;
    unsigned short* woT = (unsigned short*)w;   w += (size_t)L * D * D * 2;
    unsigned short* w1T = (unsigned short*)w;   w += (size_t)L * D * DFF * 2;
    unsigned short* w2T = (unsigned short*)w;   w += (size_t)L * DFF * D * 2;

    add_pe_kernel<<<MR * D / 4 / 256, 256, 0, stream>>>(qe, qa, pe, x_f32, x_bf, y_bf);
    wtrans_kernel<<<dim3(8, 8, L), 256, 0, stream>>>(Wk, wkT, D, D);
    wtrans_kernel<<<dim3(8, 8, L), 256, 0, stream>>>(Wv, wvT, D, D);
    wtrans_kernel<<<dim3(8, 8, L), 256, 0, stream>>>(Wo, woT, D, D);
    wtrans_kernel<<<dim3(32, 8, L), 256, 0, stream>>>(W1, w1T, D, DFF);
    wtrans_kernel<<<dim3(8, 32, L), 256, 0, stream>>>(W2, w2T, DFF, D);

    dim3 g512(64, 8), g2048(64, 16);
    for (int l = 0; l < L; l++) {
        gemm_kernel<64, false, false, false, true, false><<<g512, 256, 0, stream>>>(
            x_bf, wkT + (size_t)l * D * D, bk + l * D, nullptr, nullptr, qk_bf, MR, D, D);
        gemm_kernel<64, false, false, false, false, true><<<g512, 256, 0, stream>>>(
            y_bf, wvT + (size_t)l * D * D, bv + l * D, nullptr, nullptr, vt_bf, MR, D, D);
        attn_kernel<<<B * H * 16, 256, 0, stream>>>(qk_bf, vt_bf, o_bf);
        gemm_kernel<64, false, true, true, false, false><<<g512, 256, 0, stream>>>(
            o_bf, woT + (size_t)l * D * D, bo + l * D, x_f32, t_f32, nullptr, MR, D, D);
        ln_kernel<<<MR, 256, 0, stream>>>(t_f32, l1s + l * D, l1b + l * D, x1_f32, x1_bf);
        gemm_kernel<128, true, false, false, true, false><<<g2048, 256, 0, stream>>>(
            x1_bf, w1T + (size_t)l * D * DFF, b1 + l * DFF, nullptr, nullptr, h_bf, MR, DFF, D);
        gemm_kernel<64, false, true, true, false, false><<<g512, 256, 0, stream>>>(
            h_bf, w2T + (size_t)l * DFF * D, b2 + l * D, x1_f32, t_f32, nullptr, MR, D, DFF);
        float* xo = (l == L - 1) ? (float*)d_out : x_f32;
        ln_kernel<<<MR, 256, 0, stream>>>(t_f32, l2s + l * D, l2b + l * D, xo, x_bf);
    }
}

// Round 4
// 881.944 us; speedup vs baseline: 1.2694x; 1.2694x over previous
//
#include <hip/hip_runtime.h>
#include <stdint.h>

typedef __attribute__((ext_vector_type(8))) __bf16 bf16x8;
typedef __attribute__((ext_vector_type(4))) float f32x4;
typedef __attribute__((ext_vector_type(4))) unsigned int u32x4;

constexpr int B = 8, S = 1024, D = 512, H = 8, DFF = 2048, L = 4, DK = 64;
constexpr int MR = B * S;  // 8192 rows

__device__ __forceinline__ unsigned short f2bf(float f) {
    union { float f; unsigned u; } v; v.f = f;
    unsigned u = v.u;
    u += 0x7fffu + ((u >> 16) & 1u);   // RNE
    return (unsigned short)(u >> 16);
}

__device__ __forceinline__ void gload_lds16(const void* g, void* l) {
    __builtin_amdgcn_global_load_lds(
        (const __attribute__((address_space(1))) void*)g,
        (__attribute__((address_space(3))) void*)l, 16, 0, 0);
}

// ---------------- x = qe + pe ; y = qa + pe (f32 + bf16 copies) ----------------
__global__ __launch_bounds__(256) void add_pe_kernel(
    const float* __restrict__ qe, const float* __restrict__ qa,
    const float* __restrict__ pe, float* __restrict__ x_f32,
    unsigned short* __restrict__ x_bf, unsigned short* __restrict__ y_bf) {
    int gid = blockIdx.x * 256 + threadIdx.x;
    int base = gid * 4;
    int po = base & (S * D - 1);
    float4 p = *(const float4*)(pe + po);
    float4 a = *(const float4*)(qe + base);
    float4 q = *(const float4*)(qa + base);
    float4 xv = make_float4(a.x + p.x, a.y + p.y, a.z + p.z, a.w + p.w);
    float4 yv = make_float4(q.x + p.x, q.y + p.y, q.z + p.z, q.w + p.w);
    *(float4*)(x_f32 + base) = xv;
    ushort4 xb; xb.x = f2bf(xv.x); xb.y = f2bf(xv.y); xb.z = f2bf(xv.z); xb.w = f2bf(xv.w);
    ushort4 yb; yb.x = f2bf(yv.x); yb.y = f2bf(yv.y); yb.z = f2bf(yv.z); yb.w = f2bf(yv.w);
    *(ushort4*)(x_bf + base) = xb;
    *(ushort4*)(y_bf + base) = yb;
}

// ---------------- weight prep: f32 [K,N] -> bf16 [N,K], per layer (blockIdx.z) ----------------
__global__ __launch_bounds__(256) void wtrans_kernel(
    const float* __restrict__ src, unsigned short* __restrict__ dst, int K, int N) {
    __shared__ float t[64][65];
    src += (size_t)blockIdx.z * K * N;
    dst += (size_t)blockIdx.z * K * N;
    int n0 = blockIdx.x * 64, k0 = blockIdx.y * 64;
    int tid = threadIdx.x;
    int r = tid >> 4, c4 = (tid & 15) * 4;
    #pragma unroll
    for (int rr = 0; rr < 64; rr += 16) {
        float4 v = *(const float4*)(src + (size_t)(k0 + r + rr) * N + n0 + c4);
        t[r + rr][c4] = v.x; t[r + rr][c4 + 1] = v.y;
        t[r + rr][c4 + 2] = v.z; t[r + rr][c4 + 3] = v.w;
    }
    __syncthreads();
    int n = tid >> 2, kc = (tid & 3) * 16;
    ushort4 o[4];
    #pragma unroll
    for (int g = 0; g < 4; g++) {
        o[g].x = f2bf(t[kc + g * 4 + 0][n]);
        o[g].y = f2bf(t[kc + g * 4 + 1][n]);
        o[g].z = f2bf(t[kc + g * 4 + 2][n]);
        o[g].w = f2bf(t[kc + g * 4 + 3][n]);
    }
    unsigned short* dp = dst + (size_t)(n0 + n) * K + k0 + kc;
    #pragma unroll
    for (int g = 0; g < 4; g++) *(ushort4*)(dp + g * 4) = o[g];
}

// ---------------- GEMM: out = act(A[M,K](bf16) @ Bt[N,K](bf16)^T + bias [+resid]) ----------------
template<int BN, bool RELU, bool RESID, bool OUT_F32, bool OUT_BF16, bool OUT_VT>
__global__ __launch_bounds__(256) void gemm_kernel(
    const unsigned short* __restrict__ A, const unsigned short* __restrict__ Bt,
    const float* __restrict__ bias, const float* __restrict__ resid,
    float* __restrict__ out_f32, unsigned short* __restrict__ out_bf,
    int M, int N, int K) {
    constexpr int MT = (BN == 128) ? 4 : 2;
    constexpr int WROWS = (BN == 128) ? 64 : 32;
    __shared__ unsigned short a_lds[128 * 32];
    __shared__ unsigned short b_lds[BN * 32];

    const int tid = threadIdx.x;
    const int lane = tid & 63, wid = tid >> 6;
    const int wm = (BN == 128) ? (wid >> 1) : wid;
    const int wn = (BN == 128) ? (wid & 1) : 0;
    const int l15 = lane & 15, quad = lane >> 4;
    const int m0 = blockIdx.x * 128, n0 = blockIdx.y * BN;

    f32x4 acc[MT][4];
    #pragma unroll
    for (int i = 0; i < MT; i++)
        #pragma unroll
        for (int j = 0; j < 4; j++) { f32x4 z = {0.f, 0.f, 0.f, 0.f}; acc[i][j] = z; }

    const int c0 = wid * 128 + lane, c1 = c0 + 64;
    const int r0 = c0 >> 2, kga0 = (c0 & 3) ^ (r0 & 3);
    const int r1 = c1 >> 2, kga1 = (c1 & 3) ^ (r1 & 3);
    const unsigned short* aP0 = A + (size_t)(m0 + r0) * K + kga0 * 8;
    const unsigned short* aP1 = A + (size_t)(m0 + r1) * K + kga1 * 8;
    unsigned short* aL0 = a_lds + wid * 1024;
    unsigned short* aL1 = aL0 + 512;

    const unsigned short *bP0, *bP1;
    unsigned short *bL0, *bL1;
    if (BN == 128) {
        bP0 = Bt + (size_t)(n0 + r0) * K + kga0 * 8;
        bP1 = Bt + (size_t)(n0 + r1) * K + kga1 * 8;
        bL0 = b_lds + wid * 1024;
        bL1 = bL0 + 512;
    } else {
        int cb = tid, rb = cb >> 2, kgb = (cb & 3) ^ (rb & 3);
        bP0 = Bt + (size_t)(n0 + rb) * K + kgb * 8;
        bP1 = nullptr;
        bL0 = b_lds + wid * 512;
        bL1 = nullptr;
    }

    for (int k0 = 0; k0 < K; k0 += 32) {
        gload_lds16(aP0 + k0, aL0);
        gload_lds16(aP1 + k0, aL1);
        gload_lds16(bP0 + k0, bL0);
        if (BN == 128) gload_lds16(bP1 + k0, bL1);
        __syncthreads();

        bf16x8 af[MT], bfv[4];
        #pragma unroll
        for (int mt = 0; mt < MT; mt++) {
            int row = wm * WROWS + mt * 16 + l15;
            af[mt] = *(const bf16x8*)&a_lds[row * 32 + ((quad ^ (row & 3)) * 8)];
        }
        #pragma unroll
        for (int nt = 0; nt < 4; nt++) {
            int row = wn * 64 + nt * 16 + l15;
            bfv[nt] = *(const bf16x8*)&b_lds[row * 32 + ((quad ^ (row & 3)) * 8)];
        }
        #pragma unroll
        for (int mt = 0; mt < MT; mt++)
            #pragma unroll
            for (int nt = 0; nt < 4; nt++)
                acc[mt][nt] = __builtin_amdgcn_mfma_f32_16x16x32_bf16(af[mt], bfv[nt], acc[mt][nt], 0, 0, 0);
        __syncthreads();
    }

    #pragma unroll
    for (int nt = 0; nt < 4; nt++) {
        int col = n0 + wn * 64 + nt * 16 + l15;
        float bv = bias[col];
        #pragma unroll
        for (int mt = 0; mt < MT; mt++) {
            int row0 = m0 + wm * WROWS + mt * 16 + quad * 4;
            if (OUT_VT) {
                int hh = col >> 6, d = col & 63;
                int bb = row0 >> 10, s0 = row0 & 1023;
                ushort4 o;
                o.x = f2bf(acc[mt][nt][0] + bv);
                o.y = f2bf(acc[mt][nt][1] + bv);
                o.z = f2bf(acc[mt][nt][2] + bv);
                o.w = f2bf(acc[mt][nt][3] + bv);
                *(ushort4*)(out_bf + ((size_t)(bb * H + hh) * DK + d) * S + s0) = o;
            } else {
                #pragma unroll
                for (int r = 0; r < 4; r++) {
                    int row = row0 + r;
                    float v = acc[mt][nt][r] + bv;
                    if (RESID) v += resid[(size_t)row * N + col];
                    if (RELU) v = fmaxf(v, 0.f);
                    size_t o = (size_t)row * N + col;
                    if (OUT_F32) out_f32[o] = v;
                    if (OUT_BF16) out_bf[o] = f2bf(v);
                }
            }
        }
    }
}

// ---------------- LayerNorm over D=512, one block per row ----------------
__global__ __launch_bounds__(256) void ln_kernel(
    const float* __restrict__ in, const float* __restrict__ gamma,
    const float* __restrict__ beta, float* __restrict__ out_f32,
    unsigned short* __restrict__ out_bf) {
    __shared__ float red[8];
    int row = blockIdx.x, tid = threadIdx.x;
    const float* p = in + (size_t)row * D;
    float2 v = *(const float2*)(p + tid * 2);
    float s = v.x + v.y;
    float q = v.x * v.x + v.y * v.y;
    #pragma unroll
    for (int off = 32; off > 0; off >>= 1) {
        s += __shfl_xor(s, off);
        q += __shfl_xor(q, off);
    }
    int wid = tid >> 6, lane = tid & 63;
    if (lane == 0) { red[wid] = s; red[4 + wid] = q; }
    __syncthreads();
    s = red[0] + red[1] + red[2] + red[3];
    q = red[4] + red[5] + red[6] + red[7];
    float mean = s * (1.f / D);
    float var = q * (1.f / D) - mean * mean;
    float inv = rsqrtf(var + 1e-5f);
    int c = tid * 2;
    float2 g = *(const float2*)(gamma + c);
    float2 bb = *(const float2*)(beta + c);
    float o0 = (v.x - mean) * inv * g.x + bb.x;
    float o1 = (v.y - mean) * inv * g.y + bb.y;
    *(float2*)(out_f32 + (size_t)row * D + c) = make_float2(o0, o1);
    ushort2 ob; ob.x = f2bf(o0); ob.y = f2bf(o1);
    *(ushort2*)(out_bf + (size_t)row * D + c) = ob;
}

// ---------------- Flash attention: LDS-staged K/V, lane-uniform softmax ----------------
// Sc^T = K.Q^T. Block = 128 q rows (wave: 32 q via 2 B-frags), kt tiles of 64.
__global__ __launch_bounds__(256, 2) void attn_kernel(
    const unsigned short* __restrict__ qk, const unsigned short* __restrict__ vt,
    unsigned short* __restrict__ ob) {
    __shared__ unsigned short k_lds[64 * 64];
    __shared__ unsigned short v_lds[64 * 64];
    __shared__ unsigned short p_lds[128 * 72];   // per-wave P rows; reused as O^T in epilogue

    int bx = blockIdx.x;
    int qtb = 7 - (bx & 7);          // big tiles first
    int h = (bx >> 3) & 7, b = bx >> 6;
    int tid = threadIdx.x, lane = tid & 63, wid = tid >> 6;
    int l15 = lane & 15, quad = lane >> 4;
    const int rowbase = b * S, colbase = h * DK;
    const unsigned short* kbase = qk + (size_t)rowbase * D + colbase;
    const unsigned short* vbase = vt + (size_t)(b * H + h) * (DK * S);

    // Q B-frags (fixed): lane holds Q[q=l15][d=kh*32+quad*8+j]
    bf16x8 qf[2][2];
    #pragma unroll
    for (int u = 0; u < 2; u++) {
        const unsigned short* qrow =
            qk + (size_t)(rowbase + qtb * 128 + wid * 32 + u * 16 + l15) * D + colbase;
        qf[u][0] = *(const bf16x8*)(qrow + quad * 8);
        qf[u][1] = *(const bf16x8*)(qrow + 32 + quad * 8);
    }

    // staging: 512 chunks (16B) per tile; chunk c -> row=c>>3, group swizzled
    const int c0 = wid * 64 + lane, c1 = c0 + 256;
    const int r0 = c0 >> 3, g0 = c0 & 7, gs0 = (g0 & 4) | ((g0 & 3) ^ (r0 & 3));
    const int r1 = c1 >> 3, g1 = c1 & 7, gs1 = (g1 & 4) | ((g1 & 3) ^ (r1 & 3));
    unsigned short* kL0 = k_lds + wid * 512;
    unsigned short* kL1 = k_lds + 2048 + wid * 512;
    unsigned short* vL0 = v_lds + wid * 512;
    unsigned short* vL1 = v_lds + 2048 + wid * 512;

    float m_r[2] = {-1e30f, -1e30f}, l_r[2] = {0.f, 0.f};
    f32x4 o_acc[2][4];
    #pragma unroll
    for (int u = 0; u < 2; u++)
        #pragma unroll
        for (int i = 0; i < 4; i++) { f32x4 z = {0.f, 0.f, 0.f, 0.f}; o_acc[u][i] = z; }

    const int ktmax = 2 * qtb + 1;
    for (int kt = 0; kt <= ktmax; kt++) {
        gload_lds16(kbase + (size_t)(kt * 64 + r0) * D + gs0 * 8, kL0);
        gload_lds16(kbase + (size_t)(kt * 64 + r1) * D + gs1 * 8, kL1);
        gload_lds16(vbase + (size_t)r0 * S + kt * 64 + gs0 * 8, vL0);
        gload_lds16(vbase + (size_t)r1 * S + kt * 64 + gs1 * 8, vL1);
        __syncthreads();

        #pragma unroll
        for (int u = 0; u < 2; u++) {
            const int qbase = qtb * 128 + wid * 32 + u * 16;
            if (kt * 64 >= qbase + 16) continue;   // wave-uniform: fully masked
            const int gi = qbase + l15;

            // scores Sc^T: A = K rows (s), B = Q (q)
            f32x4 s_acc[4];
            bool live[4];
            #pragma unroll
            for (int mt = 0; mt < 4; mt++) {
                live[mt] = (kt * 64 + mt * 16) < (qbase + 16);
                if (live[mt]) {
                    int row = mt * 16 + l15;
                    int sw = (quad ^ (row & 3)) * 8;
                    bf16x8 ka0 = *(const bf16x8*)&k_lds[row * 64 + sw];
                    bf16x8 ka1 = *(const bf16x8*)&k_lds[row * 64 + sw + 32];
                    f32x4 a = {0.f, 0.f, 0.f, 0.f};
                    a = __builtin_amdgcn_mfma_f32_16x16x32_bf16(ka0, qf[u][0], a, 0, 0, 0);
                    a = __builtin_amdgcn_mfma_f32_16x16x32_bf16(ka1, qf[u][1], a, 0, 0, 0);
                    s_acc[mt] = a;
                }
            }

            // mask + scale + online softmax (q = l15, lane-uniform state)
            float p[4][4];
            float mx = -1e30f;
            #pragma unroll
            for (int mt = 0; mt < 4; mt++) {
                if (live[mt]) {
                    #pragma unroll
                    for (int r = 0; r < 4; r++) {
                        int gj = kt * 64 + mt * 16 + quad * 4 + r;
                        float val = s_acc[mt][r] * 0.125f;
                        if (gj >= gi) val = -1e30f;
                        p[mt][r] = val;
                        mx = fmaxf(mx, val);
                    }
                }
            }
            mx = fmaxf(mx, __shfl_xor(mx, 16));
            mx = fmaxf(mx, __shfl_xor(mx, 32));
            float m_new = fmaxf(m_r[u], mx);
            float alpha = __expf(m_r[u] - m_new);
            float ls = 0.f;
            #pragma unroll
            for (int mt = 0; mt < 4; mt++) {
                #pragma unroll
                for (int r = 0; r < 4; r++) {
                    float pv = live[mt] ? __expf(p[mt][r] - m_new) : 0.f;
                    p[mt][r] = pv;
                    ls += pv;
                }
            }
            ls += __shfl_xor(ls, 16);
            ls += __shfl_xor(ls, 32);
            l_r[u] = l_r[u] * alpha + ls;
            m_r[u] = m_new;

            // P^T (C-layout) -> PV B-frag via per-wave LDS roundtrip (same-wave dep, no barrier)
            const int ql = wid * 32 + u * 16 + l15;
            #pragma unroll
            for (int mt = 0; mt < 4; mt++) {
                uint2 w;
                w.x = (unsigned)f2bf(p[mt][0]) | ((unsigned)f2bf(p[mt][1]) << 16);
                w.y = (unsigned)f2bf(p[mt][2]) | ((unsigned)f2bf(p[mt][3]) << 16);
                *(uint2*)&p_lds[ql * 72 + mt * 16 + quad * 4] = w;
            }
            bf16x8 pb0 = *(const bf16x8*)&p_lds[ql * 72 + quad * 8];
            bf16x8 pb1 = *(const bf16x8*)&p_lds[ql * 72 + 32 + quad * 8];

            // rescale + PV: O^T += V^T . P'
            #pragma unroll
            for (int mt = 0; mt < 4; mt++)
                #pragma unroll
                for (int r = 0; r < 4; r++)
                    o_acc[u][mt][r] *= alpha;
            #pragma unroll
            for (int mt = 0; mt < 4; mt++) {
                int row = mt * 16 + l15;
                int sw = (quad ^ (row & 3)) * 8;
                bf16x8 va0 = *(const bf16x8*)&v_lds[row * 64 + sw];
                bf16x8 va1 = *(const bf16x8*)&v_lds[row * 64 + sw + 32];
                o_acc[u][mt] = __builtin_amdgcn_mfma_f32_16x16x32_bf16(va0, pb0, o_acc[u][mt], 0, 0, 0);
                o_acc[u][mt] = __builtin_amdgcn_mfma_f32_16x16x32_bf16(va1, pb1, o_acc[u][mt], 0, 0, 0);
            }
        }
        __syncthreads();
    }

    // epilogue: O^T -> p_lds as O[q][d] (own rows only: no barrier needed before write)
    #pragma unroll
    for (int u = 0; u < 2; u++) {
        float inv_l = 1.f / l_r[u];
        int ql = wid * 32 + u * 16 + l15;
        #pragma unroll
        for (int mt = 0; mt < 4; mt++) {
            ushort4 o;
            o.x = f2bf(o_acc[u][mt][0] * inv_l);
            o.y = f2bf(o_acc[u][mt][1] * inv_l);
            o.z = f2bf(o_acc[u][mt][2] * inv_l);
            o.w = f2bf(o_acc[u][mt][3] * inv_l);
            *(ushort4*)&p_lds[ql * 72 + mt * 16 + quad * 4] = o;
        }
    }
    __syncthreads();
    int j = tid >> 1, cc = (tid & 1) * 32;
    int si = qtb * 128 + j;
    unsigned short* dst = ob + (size_t)(rowbase + si) * D + colbase + cc;
    if (si == 0) {
        u32x4 z = {0u, 0u, 0u, 0u};
        *(u32x4*)dst = z;
        *(u32x4*)(dst + 8) = z;
        *(u32x4*)(dst + 16) = z;
        *(u32x4*)(dst + 24) = z;
    } else {
        *(bf16x8*)dst        = *(const bf16x8*)&p_lds[j * 72 + cc];
        *(bf16x8*)(dst + 8)  = *(const bf16x8*)&p_lds[j * 72 + cc + 8];
        *(bf16x8*)(dst + 16) = *(const bf16x8*)&p_lds[j * 72 + cc + 16];
        *(bf16x8*)(dst + 24) = *(const bf16x8*)&p_lds[j * 72 + cc + 24];
    }
}

// ---------------- driver ----------------
extern "C" void kernel_launch(void* const* d_in, const int* in_sizes, int n_in,
                              void* d_out, int out_size, void* d_ws, size_t ws_size,
                              hipStream_t stream) {
    (void)in_sizes; (void)n_in; (void)out_size; (void)ws_size;
    const float* qe  = (const float*)d_in[0];
    const float* qa  = (const float*)d_in[1];
    const float* pe  = (const float*)d_in[2];
    const float* Wk  = (const float*)d_in[3];
    const float* bk  = (const float*)d_in[4];
    const float* Wv  = (const float*)d_in[5];
    const float* bv  = (const float*)d_in[6];
    const float* Wo  = (const float*)d_in[7];
    const float* bo  = (const float*)d_in[8];
    const float* l1s = (const float*)d_in[9];
    const float* l1b = (const float*)d_in[10];
    const float* W1  = (const float*)d_in[11];
    const float* b1  = (const float*)d_in[12];
    const float* W2  = (const float*)d_in[13];
    const float* b2  = (const float*)d_in[14];
    const float* l2s = (const float*)d_in[15];
    const float* l2b = (const float*)d_in[16];

    char* w = (char*)d_ws;
    float* x_f32  = (float*)w;           w += (size_t)MR * D * 4;
    float* t_f32  = (float*)w;           w += (size_t)MR * D * 4;
    float* x1_f32 = (float*)w;           w += (size_t)MR * D * 4;
    unsigned short* x_bf  = (unsigned short*)w; w += (size_t)MR * D * 2;
    unsigned short* y_bf  = (unsigned short*)w; w += (size_t)MR * D * 2;
    unsigned short* qk_bf = (unsigned short*)w; w += (size_t)MR * D * 2;
    unsigned short* vt_bf = (unsigned short*)w; w += (size_t)MR * D * 2;  // V^T [B,H,DK,S]
    unsigned short* o_bf  = (unsigned short*)w; w += (size_t)MR * D * 2;
    unsigned short* x1_bf = (unsigned short*)w; w += (size_t)MR * D * 2;
    unsigned short* h_bf  = (unsigned short*)w; w += (size_t)MR * DFF * 2;
    unsigned short* wkT = (unsigned short*)w;   w += (size_t)L * D * D * 2;
    unsigned short* wvT = (unsigned short*)w;   w += (size_t)L * D * D * 2;
    unsigned short* woT = (unsigned short*)w;   w += (size_t)L * D * D * 2;
    unsigned short* w1T = (unsigned short*)w;   w += (size_t)L * D * DFF * 2;
    unsigned short* w2T = (unsigned short*)w;   w += (size_t)L * DFF * D * 2;

    add_pe_kernel<<<MR * D / 4 / 256, 256, 0, stream>>>(qe, qa, pe, x_f32, x_bf, y_bf);
    wtrans_kernel<<<dim3(8, 8, L), 256, 0, stream>>>(Wk, wkT, D, D);
    wtrans_kernel<<<dim3(8, 8, L), 256, 0, stream>>>(Wv, wvT, D, D);
    wtrans_kernel<<<dim3(8, 8, L), 256, 0, stream>>>(Wo, woT, D, D);
    wtrans_kernel<<<dim3(32, 8, L), 256, 0, stream>>>(W1, w1T, D, DFF);
    wtrans_kernel<<<dim3(8, 32, L), 256, 0, stream>>>(W2, w2T, DFF, D);

    dim3 g512(64, 8), g2048(64, 16);
    for (int l = 0; l < L; l++) {
        gemm_kernel<64, false, false, false, true, false><<<g512, 256, 0, stream>>>(
            x_bf, wkT + (size_t)l * D * D, bk + l * D, nullptr, nullptr, qk_bf, MR, D, D);
        gemm_kernel<64, false, false, false, false, true><<<g512, 256, 0, stream>>>(
            y_bf, wvT + (size_t)l * D * D, bv + l * D, nullptr, nullptr, vt_bf, MR, D, D);
        attn_kernel<<<B * H * 8, 256, 0, stream>>>(qk_bf, vt_bf, o_bf);
        gemm_kernel<64, false, true, true, false, false><<<g512, 256, 0, stream>>>(
            o_bf, woT + (size_t)l * D * D, bo + l * D, x_f32, t_f32, nullptr, MR, D, D);
        ln_kernel<<<MR, 256, 0, stream>>>(t_f32, l1s + l * D, l1b + l * D, x1_f32, x1_bf);
        gemm_kernel<128, true, false, false, true, false><<<g2048, 256, 0, stream>>>(
            x1_bf, w1T + (size_t)l * D * DFF, b1 + l * DFF, nullptr, nullptr, h_bf, MR, DFF, D);
        gemm_kernel<64, false, true, true, false, false><<<g512, 256, 0, stream>>>(
            h_bf, w2T + (size_t)l * DFF * D, b2 + l * D, x1_f32, t_f32, nullptr, MR, D, DFF);
        float* xo = (l == L - 1) ? (float*)d_out : x_f32;
        ln_kernel<<<MR, 256, 0, stream>>>(t_f32, l2s + l * D, l2b + l * D, xo, x_bf);
    }
}